// Round 7
// baseline (232.464 us; speedup 1.0000x reference)
//
#include <hip/hip_runtime.h>
#include <hip/hip_fp16.h>

// Fused Conv3d(3->16, 3x3x3, VALID) + bias + channel softmax + maxpool(4,4,4)/4.
// x: [512,3,16,32,32] f32, w: [16,3,3,3,3] f32, b: [16] f32 -> out [512,16,3,7,7] f32
//
// R17: R15/R16 multi-site amortization spilled twice (WRITE_SIZE 187/111 MB
// scratch) -- abandoned; base is the verified R14 structure (74.6 us, 48 VGPR,
// WRITE 16.6 MB). Changes:
//  (a) batched epilogue reduction: all 7 tile-sums computed first (exp2 results
//      overwrite dead acc regs), then 7x shfl_xor(16) | 7 adds | 7x shfl_xor(32)
//      | 7 adds | 7 rcps -- the 14 DS round-trips pipeline instead of
//      serializing per tile (~800cy dependent-latency cut per wave).
//  (b) log2(e) folded into weights+bias -> epilogue exp is raw v_exp_f32.
//  (c) __launch_bounds__(256,6): VGPR cap 84 gives the epilogue temps room
//      without spilling (explicit control: WRITE_SIZE must stay ~16.6 MB).
// Main loop identical to R14: K=16 MFMA, 2 shift-copies (copy1 built
// in-register via alignbit during staging), 1 ds_read2_b32 gather per MFMA,
// fence-pinned double buffer, DPP quad-max pool, LDS reused as pool buffer.

typedef _Float16 half4 __attribute__((ext_vector_type(4)));
typedef float f32x4 __attribute__((ext_vector_type(4)));
union H4 { int2 i; half4 h; };

template <int CTRL>
__device__ __forceinline__ float dpp_max(float x) {
  int xi = __builtin_bit_cast(int, x);
  int yi = __builtin_amdgcn_update_dpp(xi, xi, CTRL, 0xf, 0xf, false);
  return fmaxf(x, __builtin_bit_cast(float, yi));
}
// quad_perm ctrls: xor1 = [1,0,3,2] = 0xB1, xor2 = [2,3,0,1] = 0x4E

// Frag-ready weights for K=16, pre-scaled by log2(e): wsA[v][lane] = 4 halves
// A[c=lane&15][k=16v+4g+j], tap G = 4v+g, kw = j; zero for G>=27 or kw==3.
__global__ void wtrans(const float* __restrict__ w, int2* __restrict__ wsA) {
  int t = threadIdx.x;            // 448 threads: v = t>>6, lane = t&63
  if (t >= 448) return;
  int v = t >> 6, l = t & 63;
  int c = l & 15, g = l >> 4;
  int G = 4 * v + g;
  unsigned hh[4];
  for (int j = 0; j < 4; ++j) {
    float val = (G < 27 && j < 3) ? w[c * 81 + G * 3 + j] * 1.44269504088896f
                                  : 0.0f;
    __half h = __float2half(val);
    hh[j] = (unsigned)__half_as_ushort(h);
  }
  int2 o;
  o.x = (int)(hh[0] | (hh[1] << 16));
  o.y = (int)(hh[2] | (hh[3] << 16));
  wsA[v * 64 + l] = o;
}

__global__ __launch_bounds__(256, 6) void conv_sm_pool(
    const float* __restrict__ x, const int2* __restrict__ wsA,
    const float* __restrict__ b, float* __restrict__ out) {
  // 2 shifted copies of the 3456-half tile stream (copy1 = shift-1-half),
  // copy stride 1736 ints. Rows unpadded: row (cin,ld,lh) = 32 halves = 16 ints.
  // Gather: half-window Q..Q+3 -> copy Q&1, int index Q>>1 via ds_read2_b32.
  // After the main loop, reused as pool buffer [dd*4+dh][pw][c].
  __shared__ int lds[3472];

  const int tid = threadIdx.x;
  const int blk = blockIdx.x;
  const int n = blk / 21, rr = blk % 21, pd = rr / 7, ph = rr % 7;

  const int lane = tid & 63;
  const int dd = tid >> 6;            // wave = one dd slice (0..3)
  const int l15 = lane & 15, g = lane >> 4;

  // ---- setup hoisted above staging: global loads + index math ----
  H4 wa[7];
#pragma unroll
  for (int v = 0; v < 7; ++v) wa[v].i = wsA[v * 64 + lane];

  float4 b4 = *reinterpret_cast<const float4*>(b + 4 * g);

  // tap-group int offsets: T = cin*576 + kd*96 + kh*16 for G = 4v+g (clamped)
  int tvi[7];
#pragma unroll
  for (int v = 0; v < 7; ++v) {
    int G = 4 * v + g;
    if (G > 26) G = 26;
    int cin = G / 9, r = G % 9;
    tvi[v] = cin * 576 + (r / 3) * 96 + (r % 3) * 16;
  }

  // position bases: P = dd*192 + dh*32 + wp (halves); pbi = (P>>1)+(P&1)*1736
  int pbi[7];
#pragma unroll
  for (int tl = 0; tl < 7; ++tl) {
    int rem = tl * 16;
    int dh0 = rem / 28, rem28 = rem % 28;
    int bump = (rem28 + l15) >= 28 ? 1 : 0;
    int P = dd * 192 + (dh0 + bump) * 32 + (rem28 + l15 - 28 * bump);
    pbi[tl] = (P >> 1) + (P & 1) * 1736;
  }

  // ---- stage both copies, loop-free: 216 threads, one (row,seg) each ----
  const float* xb = x + ((size_t)n * 3 * 16 * 32 * 32)
                  + (size_t)(4 * pd) * 1024 + (size_t)(4 * ph) * 32;
  if (tid < 216) {
    int row = tid >> 1, seg = tid & 1;      // row = cin*36 + ld*6 + lh
    int lh = row % 6, t2 = row / 6, ld = t2 % 6, cin = t2 / 6;
    const float* src = &xb[((cin * 16 + ld) * 32 + lh) * 32 + seg * 16];
    float4 f0 = *reinterpret_cast<const float4*>(src);
    float4 f1 = *reinterpret_cast<const float4*>(src + 4);
    float4 f2 = *reinterpret_cast<const float4*>(src + 8);
    float4 f3 = *reinterpret_cast<const float4*>(src + 12);
    float ex = src[16];
    int c[8];
    __half2 h;
    h = __float22half2_rn(make_float2(f0.x, f0.y)); c[0] = *reinterpret_cast<int*>(&h);
    h = __float22half2_rn(make_float2(f0.z, f0.w)); c[1] = *reinterpret_cast<int*>(&h);
    h = __float22half2_rn(make_float2(f1.x, f1.y)); c[2] = *reinterpret_cast<int*>(&h);
    h = __float22half2_rn(make_float2(f1.z, f1.w)); c[3] = *reinterpret_cast<int*>(&h);
    h = __float22half2_rn(make_float2(f2.x, f2.y)); c[4] = *reinterpret_cast<int*>(&h);
    h = __float22half2_rn(make_float2(f2.z, f2.w)); c[5] = *reinterpret_cast<int*>(&h);
    h = __float22half2_rn(make_float2(f3.x, f3.y)); c[6] = *reinterpret_cast<int*>(&h);
    h = __float22half2_rn(make_float2(f3.z, f3.w)); c[7] = *reinterpret_cast<int*>(&h);
    int eh = (int)__half_as_ushort(__float2half(ex));
    int s[8];
#pragma unroll
    for (int k = 0; k < 7; ++k) s[k] = __builtin_amdgcn_alignbit(c[k + 1], c[k], 16);
    s[7] = __builtin_amdgcn_alignbit(eh, c[7], 16);
    int li = row * 16 + seg * 8;
    int4 w0; w0.x = c[0]; w0.y = c[1]; w0.z = c[2]; w0.w = c[3];
    int4 w1; w1.x = c[4]; w1.y = c[5]; w1.z = c[6]; w1.w = c[7];
    *reinterpret_cast<int4*>(&lds[li])     = w0;
    *reinterpret_cast<int4*>(&lds[li + 4]) = w1;
    int4 w2; w2.x = s[0]; w2.y = s[1]; w2.z = s[2]; w2.w = s[3];
    int4 w3; w3.x = s[4]; w3.y = s[5]; w3.z = s[6]; w3.w = s[7];
    *reinterpret_cast<int4*>(&lds[1736 + li])     = w2;
    *reinterpret_cast<int4*>(&lds[1736 + li + 4]) = w3;
  }
  __syncthreads();

  // acc init with bias (row = channel = 4g+q), log2e pre-scaled
  f32x4 acc[7];
  f32x4 binit;
  binit[0] = b4.x * 1.44269504088896f;
  binit[1] = b4.y * 1.44269504088896f;
  binit[2] = b4.z * 1.44269504088896f;
  binit[3] = b4.w * 1.44269504088896f;
#pragma unroll
  for (int tl = 0; tl < 7; ++tl) acc[tl] = binit;

  // ---- main: 7 K-windows x 7 N-tiles, double-buffered, fence-pinned ----
  H4 bfA[7], bfB[7];
#pragma unroll
  for (int tl = 0; tl < 7; ++tl) {
    const int* p = &lds[pbi[tl] + tvi[0]];
    bfA[tl].i.x = p[0]; bfA[tl].i.y = p[1];
  }
  __builtin_amdgcn_sched_barrier(0);
#pragma unroll
  for (int vv = 0; vv < 3; ++vv) {
    const int v0 = 2 * vv, v1 = 2 * vv + 1, v2 = 2 * vv + 2;
#pragma unroll
    for (int tl = 0; tl < 7; ++tl) {
      const int* p = &lds[pbi[tl] + tvi[v1]];
      bfB[tl].i.x = p[0]; bfB[tl].i.y = p[1];
    }
    __builtin_amdgcn_sched_barrier(0);
#pragma unroll
    for (int tl = 0; tl < 7; ++tl)
      acc[tl] = __builtin_amdgcn_mfma_f32_16x16x16f16(wa[v0].h, bfA[tl].h, acc[tl], 0, 0, 0);
    __builtin_amdgcn_sched_barrier(0);
#pragma unroll
    for (int tl = 0; tl < 7; ++tl) {
      const int* p = &lds[pbi[tl] + tvi[v2]];
      bfA[tl].i.x = p[0]; bfA[tl].i.y = p[1];
    }
    __builtin_amdgcn_sched_barrier(0);
#pragma unroll
    for (int tl = 0; tl < 7; ++tl)
      acc[tl] = __builtin_amdgcn_mfma_f32_16x16x16f16(wa[v1].h, bfB[tl].h, acc[tl], 0, 0, 0);
    __builtin_amdgcn_sched_barrier(0);
  }
#pragma unroll
  for (int tl = 0; tl < 7; ++tl)
    acc[tl] = __builtin_amdgcn_mfma_f32_16x16x16f16(wa[6].h, bfA[tl].h, acc[tl], 0, 0, 0);

  // ---- epilogue: softmax over channels (batched reductions), pool ----
  __syncthreads();      // all LDS tile reads done; reuse lds as pool buffer
  float* pool2 = reinterpret_cast<float*>(lds);   // [dd*4+dh][pw][c]

  // phase 1: exp2 in place (acc regs reused), per-tile channel-group sums
  float s4[7];
#pragma unroll
  for (int tl = 0; tl < 7; ++tl) {
#pragma unroll
    for (int q = 0; q < 4; ++q) acc[tl][q] = __builtin_amdgcn_exp2f(acc[tl][q]);
    s4[tl] = (acc[tl][0] + acc[tl][1]) + (acc[tl][2] + acc[tl][3]);
  }
  // phase 2: batched cross-group butterflies (7 independent chains pipeline)
  float t7[7];
#pragma unroll
  for (int tl = 0; tl < 7; ++tl) t7[tl] = __shfl_xor(s4[tl], 16, 64);
#pragma unroll
  for (int tl = 0; tl < 7; ++tl) s4[tl] += t7[tl];
#pragma unroll
  for (int tl = 0; tl < 7; ++tl) t7[tl] = __shfl_xor(s4[tl], 32, 64);
#pragma unroll
  for (int tl = 0; tl < 7; ++tl) s4[tl] += t7[tl];
#pragma unroll
  for (int tl = 0; tl < 7; ++tl) s4[tl] = __builtin_amdgcn_rcpf(s4[tl]);

  // phase 3: normalize, DPP quad-max, pool write
#pragma unroll
  for (int tl = 0; tl < 7; ++tl) {
    float pm[4];
#pragma unroll
    for (int q = 0; q < 4; ++q) pm[q] = acc[tl][q] * s4[tl];
#pragma unroll
    for (int q = 0; q < 4; ++q) {
      pm[q] = dpp_max<0xB1>(pm[q]);   // wp xor1
      pm[q] = dpp_max<0x4E>(pm[q]);   // wp xor2
    }
    if ((l15 & 3) == 0) {
      int rem = tl * 16;
      int dh0 = rem / 28, rem28 = rem % 28;
      int bump = (rem28 + l15) >= 28 ? 1 : 0;
      int dh = dh0 + bump;
      int pw = (rem28 + l15 - 28 * bump) >> 2;
      float4 val = {pm[0], pm[1], pm[2], pm[3]};
      *reinterpret_cast<float4*>(&pool2[(((dd * 4 + dh) * 7 + pw) << 4) + 4 * g]) = val;
    }
  }
  __syncthreads();

  // tail: pair (tid, tid^1) split the 16 slots 8/8, DPP pair-max
  if (tid < 224) {
    int idx = tid >> 1, h = tid & 1;
    int c = idx / 7, pw = idx % 7;
    float m = pool2[(((h * 8) * 7 + pw) << 4) + c];
#pragma unroll
    for (int s2 = 1; s2 < 8; ++s2)
      m = fmaxf(m, pool2[(((h * 8 + s2) * 7 + pw) << 4) + c]);
    m = dpp_max<0xB1>(m);   // combine with partner (lanes 2k,2k+1)
    if (h == 0)
      out[(((size_t)n * 16 + c) * 3 + pd) * 49 + (size_t)ph * 7 + pw] = m;
  }
}

extern "C" void kernel_launch(void* const* d_in, const int* in_sizes, int n_in,
                              void* d_out, int out_size, void* d_ws, size_t ws_size,
                              hipStream_t stream) {
  const float* x = (const float*)d_in[0];
  const float* w = (const float*)d_in[1];
  const float* b = (const float*)d_in[2];
  float* out = (float*)d_out;
  int2* wsA = (int2*)d_ws;   // 7 windows * 64 lanes * 8 B = 3584 B
  (void)in_sizes; (void)n_in; (void)out_size; (void)ws_size;
  hipLaunchKernelGGL(wtrans, dim3(1), dim3(448), 0, stream, w, wsA);
  hipLaunchKernelGGL(conv_sm_pool, dim3(512 * 3 * 7), dim3(256), 0, stream,
                     x, wsA, b, out);
}

// Round 8
// 180.294 us; speedup vs baseline: 1.2894x; 1.2894x over previous
//
#include <hip/hip_runtime.h>
#include <hip/hip_fp16.h>

// Fused Conv3d(3->16, 3x3x3, VALID) + bias + channel softmax + maxpool(4,4,4)/4.
// x: [512,3,16,32,32] f32, w: [16,3,3,3,3] f32, b: [16] f32 -> out [512,16,3,7,7] f32
//
// R18: R17's regression was a launch-bounds-induced spill: (256,6) tightened
// the empirical VGPR cap to 40 (session trend: (256,4)->64, (256,5)->48,
// (256,6)->40) while the batched epilogue needs ~14 extra live floats ->
// 203 MB scratch writes. R18 = R17 with the proven (256,5) bounds restored.
// Changes vs R14 (74.6 us baseline), now cleanly isolated:
//  (a) batched epilogue reduction: exp2 in place over acc, 7 sums, then the
//      7 shfl_xor(16)/add, 7 shfl_xor(32)/add, 7 rcp chains pipelined.
//  (b) log2(e) folded into weights+bias -> epilogue exp is raw v_exp_f32.
// Main loop identical to R14: K=16 MFMA, 2 shift-copies (copy1 via alignbit
// at staging), 1 ds_read2_b32 gather per MFMA, fence-pinned double buffer,
// DPP quad-max pool, LDS reused as pool buffer.
// Spill control: WRITE_SIZE must be ~16.6 MB; if higher, revert (a).

typedef _Float16 half4 __attribute__((ext_vector_type(4)));
typedef float f32x4 __attribute__((ext_vector_type(4)));
union H4 { int2 i; half4 h; };

template <int CTRL>
__device__ __forceinline__ float dpp_max(float x) {
  int xi = __builtin_bit_cast(int, x);
  int yi = __builtin_amdgcn_update_dpp(xi, xi, CTRL, 0xf, 0xf, false);
  return fmaxf(x, __builtin_bit_cast(float, yi));
}
// quad_perm ctrls: xor1 = [1,0,3,2] = 0xB1, xor2 = [2,3,0,1] = 0x4E

// Frag-ready weights for K=16, pre-scaled by log2(e): wsA[v][lane] = 4 halves
// A[c=lane&15][k=16v+4g+j], tap G = 4v+g, kw = j; zero for G>=27 or kw==3.
__global__ void wtrans(const float* __restrict__ w, int2* __restrict__ wsA) {
  int t = threadIdx.x;            // 448 threads: v = t>>6, lane = t&63
  if (t >= 448) return;
  int v = t >> 6, l = t & 63;
  int c = l & 15, g = l >> 4;
  int G = 4 * v + g;
  unsigned hh[4];
  for (int j = 0; j < 4; ++j) {
    float val = (G < 27 && j < 3) ? w[c * 81 + G * 3 + j] * 1.44269504088896f
                                  : 0.0f;
    __half h = __float2half(val);
    hh[j] = (unsigned)__half_as_ushort(h);
  }
  int2 o;
  o.x = (int)(hh[0] | (hh[1] << 16));
  o.y = (int)(hh[2] | (hh[3] << 16));
  wsA[v * 64 + l] = o;
}

__global__ __launch_bounds__(256, 5) void conv_sm_pool(
    const float* __restrict__ x, const int2* __restrict__ wsA,
    const float* __restrict__ b, float* __restrict__ out) {
  // 2 shifted copies of the 3456-half tile stream (copy1 = shift-1-half),
  // copy stride 1736 ints. Rows unpadded: row (cin,ld,lh) = 32 halves = 16 ints.
  // Gather: half-window Q..Q+3 -> copy Q&1, int index Q>>1 via ds_read2_b32.
  // After the main loop, reused as pool buffer [dd*4+dh][pw][c].
  __shared__ int lds[3472];

  const int tid = threadIdx.x;
  const int blk = blockIdx.x;
  const int n = blk / 21, rr = blk % 21, pd = rr / 7, ph = rr % 7;

  const int lane = tid & 63;
  const int dd = tid >> 6;            // wave = one dd slice (0..3)
  const int l15 = lane & 15, g = lane >> 4;

  // ---- setup hoisted above staging: global loads + index math ----
  H4 wa[7];
#pragma unroll
  for (int v = 0; v < 7; ++v) wa[v].i = wsA[v * 64 + lane];

  float4 b4 = *reinterpret_cast<const float4*>(b + 4 * g);

  // tap-group int offsets: T = cin*576 + kd*96 + kh*16 for G = 4v+g (clamped)
  int tvi[7];
#pragma unroll
  for (int v = 0; v < 7; ++v) {
    int G = 4 * v + g;
    if (G > 26) G = 26;
    int cin = G / 9, r = G % 9;
    tvi[v] = cin * 576 + (r / 3) * 96 + (r % 3) * 16;
  }

  // position bases: P = dd*192 + dh*32 + wp (halves); pbi = (P>>1)+(P&1)*1736
  int pbi[7];
#pragma unroll
  for (int tl = 0; tl < 7; ++tl) {
    int rem = tl * 16;
    int dh0 = rem / 28, rem28 = rem % 28;
    int bump = (rem28 + l15) >= 28 ? 1 : 0;
    int P = dd * 192 + (dh0 + bump) * 32 + (rem28 + l15 - 28 * bump);
    pbi[tl] = (P >> 1) + (P & 1) * 1736;
  }

  // ---- stage both copies, loop-free: 216 threads, one (row,seg) each ----
  const float* xb = x + ((size_t)n * 3 * 16 * 32 * 32)
                  + (size_t)(4 * pd) * 1024 + (size_t)(4 * ph) * 32;
  if (tid < 216) {
    int row = tid >> 1, seg = tid & 1;      // row = cin*36 + ld*6 + lh
    int lh = row % 6, t2 = row / 6, ld = t2 % 6, cin = t2 / 6;
    const float* src = &xb[((cin * 16 + ld) * 32 + lh) * 32 + seg * 16];
    float4 f0 = *reinterpret_cast<const float4*>(src);
    float4 f1 = *reinterpret_cast<const float4*>(src + 4);
    float4 f2 = *reinterpret_cast<const float4*>(src + 8);
    float4 f3 = *reinterpret_cast<const float4*>(src + 12);
    float ex = src[16];
    int c[8];
    __half2 h;
    h = __float22half2_rn(make_float2(f0.x, f0.y)); c[0] = *reinterpret_cast<int*>(&h);
    h = __float22half2_rn(make_float2(f0.z, f0.w)); c[1] = *reinterpret_cast<int*>(&h);
    h = __float22half2_rn(make_float2(f1.x, f1.y)); c[2] = *reinterpret_cast<int*>(&h);
    h = __float22half2_rn(make_float2(f1.z, f1.w)); c[3] = *reinterpret_cast<int*>(&h);
    h = __float22half2_rn(make_float2(f2.x, f2.y)); c[4] = *reinterpret_cast<int*>(&h);
    h = __float22half2_rn(make_float2(f2.z, f2.w)); c[5] = *reinterpret_cast<int*>(&h);
    h = __float22half2_rn(make_float2(f3.x, f3.y)); c[6] = *reinterpret_cast<int*>(&h);
    h = __float22half2_rn(make_float2(f3.z, f3.w)); c[7] = *reinterpret_cast<int*>(&h);
    int eh = (int)__half_as_ushort(__float2half(ex));
    int s[8];
#pragma unroll
    for (int k = 0; k < 7; ++k) s[k] = __builtin_amdgcn_alignbit(c[k + 1], c[k], 16);
    s[7] = __builtin_amdgcn_alignbit(eh, c[7], 16);
    int li = row * 16 + seg * 8;
    int4 w0; w0.x = c[0]; w0.y = c[1]; w0.z = c[2]; w0.w = c[3];
    int4 w1; w1.x = c[4]; w1.y = c[5]; w1.z = c[6]; w1.w = c[7];
    *reinterpret_cast<int4*>(&lds[li])     = w0;
    *reinterpret_cast<int4*>(&lds[li + 4]) = w1;
    int4 w2; w2.x = s[0]; w2.y = s[1]; w2.z = s[2]; w2.w = s[3];
    int4 w3; w3.x = s[4]; w3.y = s[5]; w3.z = s[6]; w3.w = s[7];
    *reinterpret_cast<int4*>(&lds[1736 + li])     = w2;
    *reinterpret_cast<int4*>(&lds[1736 + li + 4]) = w3;
  }
  __syncthreads();

  // acc init with bias (row = channel = 4g+q), log2e pre-scaled
  f32x4 acc[7];
  f32x4 binit;
  binit[0] = b4.x * 1.44269504088896f;
  binit[1] = b4.y * 1.44269504088896f;
  binit[2] = b4.z * 1.44269504088896f;
  binit[3] = b4.w * 1.44269504088896f;
#pragma unroll
  for (int tl = 0; tl < 7; ++tl) acc[tl] = binit;

  // ---- main: 7 K-windows x 7 N-tiles, double-buffered, fence-pinned ----
  H4 bfA[7], bfB[7];
#pragma unroll
  for (int tl = 0; tl < 7; ++tl) {
    const int* p = &lds[pbi[tl] + tvi[0]];
    bfA[tl].i.x = p[0]; bfA[tl].i.y = p[1];
  }
  __builtin_amdgcn_sched_barrier(0);
#pragma unroll
  for (int vv = 0; vv < 3; ++vv) {
    const int v0 = 2 * vv, v1 = 2 * vv + 1, v2 = 2 * vv + 2;
#pragma unroll
    for (int tl = 0; tl < 7; ++tl) {
      const int* p = &lds[pbi[tl] + tvi[v1]];
      bfB[tl].i.x = p[0]; bfB[tl].i.y = p[1];
    }
    __builtin_amdgcn_sched_barrier(0);
#pragma unroll
    for (int tl = 0; tl < 7; ++tl)
      acc[tl] = __builtin_amdgcn_mfma_f32_16x16x16f16(wa[v0].h, bfA[tl].h, acc[tl], 0, 0, 0);
    __builtin_amdgcn_sched_barrier(0);
#pragma unroll
    for (int tl = 0; tl < 7; ++tl) {
      const int* p = &lds[pbi[tl] + tvi[v2]];
      bfA[tl].i.x = p[0]; bfA[tl].i.y = p[1];
    }
    __builtin_amdgcn_sched_barrier(0);
#pragma unroll
    for (int tl = 0; tl < 7; ++tl)
      acc[tl] = __builtin_amdgcn_mfma_f32_16x16x16f16(wa[v1].h, bfB[tl].h, acc[tl], 0, 0, 0);
    __builtin_amdgcn_sched_barrier(0);
  }
#pragma unroll
  for (int tl = 0; tl < 7; ++tl)
    acc[tl] = __builtin_amdgcn_mfma_f32_16x16x16f16(wa[6].h, bfA[tl].h, acc[tl], 0, 0, 0);

  // ---- epilogue: softmax over channels (batched reductions), pool ----
  __syncthreads();      // all LDS tile reads done; reuse lds as pool buffer
  float* pool2 = reinterpret_cast<float*>(lds);   // [dd*4+dh][pw][c]

  // phase 1: exp2 in place (acc regs reused), per-tile channel-group sums
  float s4[7];
#pragma unroll
  for (int tl = 0; tl < 7; ++tl) {
#pragma unroll
    for (int q = 0; q < 4; ++q) acc[tl][q] = __builtin_amdgcn_exp2f(acc[tl][q]);
    s4[tl] = (acc[tl][0] + acc[tl][1]) + (acc[tl][2] + acc[tl][3]);
  }
  // phase 2: batched cross-group butterflies (7 independent chains pipeline)
  float t7[7];
#pragma unroll
  for (int tl = 0; tl < 7; ++tl) t7[tl] = __shfl_xor(s4[tl], 16, 64);
#pragma unroll
  for (int tl = 0; tl < 7; ++tl) s4[tl] += t7[tl];
#pragma unroll
  for (int tl = 0; tl < 7; ++tl) t7[tl] = __shfl_xor(s4[tl], 32, 64);
#pragma unroll
  for (int tl = 0; tl < 7; ++tl) s4[tl] += t7[tl];
#pragma unroll
  for (int tl = 0; tl < 7; ++tl) s4[tl] = __builtin_amdgcn_rcpf(s4[tl]);

  // phase 3: normalize, DPP quad-max, pool write
#pragma unroll
  for (int tl = 0; tl < 7; ++tl) {
    float pm[4];
#pragma unroll
    for (int q = 0; q < 4; ++q) pm[q] = acc[tl][q] * s4[tl];
#pragma unroll
    for (int q = 0; q < 4; ++q) {
      pm[q] = dpp_max<0xB1>(pm[q]);   // wp xor1
      pm[q] = dpp_max<0x4E>(pm[q]);   // wp xor2
    }
    if ((l15 & 3) == 0) {
      int rem = tl * 16;
      int dh0 = rem / 28, rem28 = rem % 28;
      int bump = (rem28 + l15) >= 28 ? 1 : 0;
      int dh = dh0 + bump;
      int pw = (rem28 + l15 - 28 * bump) >> 2;
      float4 val = {pm[0], pm[1], pm[2], pm[3]};
      *reinterpret_cast<float4*>(&pool2[(((dd * 4 + dh) * 7 + pw) << 4) + 4 * g]) = val;
    }
  }
  __syncthreads();

  // tail: pair (tid, tid^1) split the 16 slots 8/8, DPP pair-max
  if (tid < 224) {
    int idx = tid >> 1, h = tid & 1;
    int c = idx / 7, pw = idx % 7;
    float m = pool2[(((h * 8) * 7 + pw) << 4) + c];
#pragma unroll
    for (int s2 = 1; s2 < 8; ++s2)
      m = fmaxf(m, pool2[(((h * 8 + s2) * 7 + pw) << 4) + c]);
    m = dpp_max<0xB1>(m);   // combine with partner (lanes 2k,2k+1)
    if (h == 0)
      out[(((size_t)n * 16 + c) * 3 + pd) * 49 + (size_t)ph * 7 + pw] = m;
  }
}

extern "C" void kernel_launch(void* const* d_in, const int* in_sizes, int n_in,
                              void* d_out, int out_size, void* d_ws, size_t ws_size,
                              hipStream_t stream) {
  const float* x = (const float*)d_in[0];
  const float* w = (const float*)d_in[1];
  const float* b = (const float*)d_in[2];
  float* out = (float*)d_out;
  int2* wsA = (int2*)d_ws;   // 7 windows * 64 lanes * 8 B = 3584 B
  (void)in_sizes; (void)n_in; (void)out_size; (void)ws_size;
  hipLaunchKernelGGL(wtrans, dim3(1), dim3(448), 0, stream, w, wsA);
  hipLaunchKernelGGL(conv_sm_pool, dim3(512 * 3 * 7), dim3(256), 0, stream,
                     x, wsA, b, out);
}